// Round 1
// baseline (206.319 us; speedup 1.0000x reference)
//
#include <hip/hip_runtime.h>

#define SEQ  256
#define DIM  20
#define HID  20
#define NCLS 5

__device__ __forceinline__ float fast_tanh(float x) {
    // tanh(x) = 1 - 2/(exp(2x)+1); exp(2x) = exp2(x * 2*log2(e))
    float e2x = __builtin_amdgcn_exp2f(x * 2.8853900817779268f);
    float r   = __builtin_amdgcn_rcpf(e2x + 1.0f);
    return fmaf(-2.0f, r, 1.0f);
}

__global__ __launch_bounds__(256, 1)
void rnn_fused(const int* __restrict__ x,
               const float* __restrict__ emb,
               const float* __restrict__ W_ih,
               const float* __restrict__ W_hh,
               const float* __restrict__ W_cls,
               const float* __restrict__ b_cls,
               float* __restrict__ out,
               int B)
{
    const int tid = blockIdx.x * blockDim.x + threadIdx.x;
    const int row = tid >> 2;   // batch row
    const int sub = tid & 3;    // owns hidden units [sub*5, sub*5+5)
    if (row >= B) return;
    const int u0 = sub * 5;

    // Per-thread weight rows, held in VGPRs for all 256 steps.
    float wih[5][20], whh[5][20];
#pragma unroll
    for (int u = 0; u < 5; ++u) {
#pragma unroll
        for (int d = 0; d < 20; d += 4) {
            float4 a = *reinterpret_cast<const float4*>(W_ih + (u0 + u) * 20 + d);
            wih[u][d+0] = a.x; wih[u][d+1] = a.y; wih[u][d+2] = a.z; wih[u][d+3] = a.w;
            float4 b = *reinterpret_cast<const float4*>(W_hh + (u0 + u) * 20 + d);
            whh[u][d+0] = b.x; whh[u][d+1] = b.y; whh[u][d+2] = b.z; whh[u][d+3] = b.w;
        }
    }

    float h[20];
#pragma unroll
    for (int i = 0; i < 20; ++i) h[i] = 0.0f;

    const int* xrow = x + (long)row * SEQ;
    int tokCur = xrow[0];

#pragma unroll 1
    for (int s = 0; s < SEQ; ++s) {
        // Issue embedding gather for this step first (emb rows are 16B-aligned: 20*4=80B).
        const float4* ep = reinterpret_cast<const float4*>(emb + (long)tokCur * DIM);
        float4 f0 = ep[0], f1 = ep[1], f2 = ep[2], f3 = ep[3], f4 = ep[4];
        const float flag = (tokCur != 0) ? 1.0f : 0.0f;   // padding_idx=0
        const int tokNext = xrow[(s + 1 < SEQ) ? (s + 1) : s];

        // Recurrent matvec first — 100 FMAs of latency cover for the e-loads.
        float hacc[5];
#pragma unroll
        for (int u = 0; u < 5; ++u) {
            float a = 0.0f;
#pragma unroll
            for (int d = 0; d < 20; ++d) a = fmaf(whh[u][d], h[d], a);
            hacc[u] = a;
        }

        const float ef[20] = {f0.x,f0.y,f0.z,f0.w, f1.x,f1.y,f1.z,f1.w,
                              f2.x,f2.y,f2.z,f2.w, f3.x,f3.y,f3.z,f3.w};
        float hn[5];
#pragma unroll
        for (int u = 0; u < 5; ++u) {
            float a = 0.0f;
#pragma unroll
            for (int d = 0; d < 16; ++d) a = fmaf(wih[u][d], ef[d], a);
            a = fmaf(wih[u][16], f4.x, a);
            a = fmaf(wih[u][17], f4.y, a);
            a = fmaf(wih[u][18], f4.z, a);
            a = fmaf(wih[u][19], f4.w, a);
            float pre = fmaf(flag, a, hacc[u]);
            hn[u] = fast_tanh(pre);
        }

        // Exchange: every lane of the 4-group gets the full 20-wide h.
        // h[j*5+u] comes from group-lane j; all register indices compile-time.
#pragma unroll
        for (int j = 0; j < 4; ++j) {
#pragma unroll
            for (int u = 0; u < 5; ++u) {
                h[j * 5 + u] = __shfl(hn[u], j, 4);
            }
        }
        tokCur = tokNext;
    }

    // Classifier: y = h @ W_cls^T + b_cls. Lane sub does class sub; lane 0 also class 4.
    {
        const int c = sub;
        float acc = b_cls[c];
#pragma unroll
        for (int d = 0; d < 20; ++d) acc = fmaf(W_cls[c * 20 + d], h[d], acc);
        out[(long)row * NCLS + c] = acc;
        if (sub == 0) {
            float acc4 = b_cls[4];
#pragma unroll
            for (int d = 0; d < 20; ++d) acc4 = fmaf(W_cls[4 * 20 + d], h[d], acc4);
            out[(long)row * NCLS + 4] = acc4;
        }
    }
}

extern "C" void kernel_launch(void* const* d_in, const int* in_sizes, int n_in,
                              void* d_out, int out_size, void* d_ws, size_t ws_size,
                              hipStream_t stream) {
    const int*   x     = (const int*)d_in[0];
    const float* emb   = (const float*)d_in[1];
    const float* W_ih  = (const float*)d_in[2];
    const float* W_hh  = (const float*)d_in[3];
    const float* W_cls = (const float*)d_in[4];
    const float* b_cls = (const float*)d_in[5];
    float* out = (float*)d_out;

    const int B = in_sizes[0] / SEQ;          // 16384
    const int threads = B * 4;                 // 4 lanes per row
    const int block = 256;
    const int grid = (threads + block - 1) / block;
    rnn_fused<<<grid, block, 0, stream>>>(x, emb, W_ih, W_hh, W_cls, b_cls, out, B);
}

// Round 2
// 154.713 us; speedup vs baseline: 1.3336x; 1.3336x over previous
//
#include <hip/hip_runtime.h>

#define SEQ  256
#define DIM  20
#define HID  20
#define NCLS 5

__device__ __forceinline__ float fast_tanh(float x) {
    // tanh(x) = 1 - 2/(exp(2x)+1); exp(2x) = exp2(x * 2*log2(e))
    float e2x = __builtin_amdgcn_exp2f(x * 2.8853900817779268f);
    float r   = __builtin_amdgcn_rcpf(e2x + 1.0f);
    return fmaf(-2.0f, r, 1.0f);
}

// 8 lanes per batch row: sub = lane&7.
//   ug = sub&3  -> owns hidden units [ug*5, ug*5+5)
//   kh = sub>>2 -> owns k-slice [kh*10, kh*10+10) of the dot products
// Each lane: 5x10 W_hh slice + 5x10 W_ih slice in VGPRs (100 regs),
// partial dots reduced across the two k-halves with one shfl_xor.
// Embedding rows are prefetched one full step ahead (ping-pong eA/eB).

// One RNN step. ECUR/FLAGCUR: current step's embedding slice + pad flag.
// Prefetches EPF <- emb[PFTOK] and NEXTTOK <- xrow[NEXTIDX] for the future.
#define HALF_STEP(ECUR, FLAGCUR, EPF, FLAGPF, PFTOK, NEXTIDX, NEXTTOK)        \
    {                                                                          \
        const float2* _p = (const float2*)(emb + (long)(PFTOK) * DIM + k0);    \
        float2 _e0 = _p[0], _e1 = _p[1], _e2 = _p[2], _e3 = _p[3], _e4 = _p[4];\
        FLAGPF = ((PFTOK) != 0) ? 1.0f : 0.0f;                                 \
        NEXTTOK = xrow[(NEXTIDX) < SEQ ? (NEXTIDX) : (SEQ - 1)];               \
        float _pp[5];                                                          \
        _Pragma("unroll")                                                      \
        for (int u = 0; u < 5; ++u) {                                          \
            float _a = 0.0f, _c = 0.0f;                                        \
            _Pragma("unroll")                                                  \
            for (int k = 0; k < 10; ++k) {                                     \
                _a = fmaf(whh[u][k], h[k], _a);                                \
                _c = fmaf(wih[u][k], ECUR[k], _c);                             \
            }                                                                  \
            _pp[u] = fmaf(FLAGCUR, _c, _a);                                    \
        }                                                                      \
        _Pragma("unroll")                                                      \
        for (int u = 0; u < 5; ++u) {                                          \
            _pp[u] += __shfl_xor(_pp[u], 4, 8);                                \
            _pp[u] = fast_tanh(_pp[u]);                                        \
        }                                                                      \
        _Pragma("unroll")                                                      \
        for (int i = 0; i < 10; ++i)                                           \
            h[i] = __shfl(_pp[i % 5], kh * 2 + i / 5, 8);                      \
        EPF[0] = _e0.x; EPF[1] = _e0.y; EPF[2] = _e1.x; EPF[3] = _e1.y;        \
        EPF[4] = _e2.x; EPF[5] = _e2.y; EPF[6] = _e3.x; EPF[7] = _e3.y;        \
        EPF[8] = _e4.x; EPF[9] = _e4.y;                                        \
    }

__global__ __launch_bounds__(256, 2)
void rnn_fused(const int* __restrict__ x,
               const float* __restrict__ emb,
               const float* __restrict__ W_ih,
               const float* __restrict__ W_hh,
               const float* __restrict__ W_cls,
               const float* __restrict__ b_cls,
               float* __restrict__ out,
               int B)
{
    const int tid = blockIdx.x * blockDim.x + threadIdx.x;
    const int row = tid >> 3;
    const int sub = tid & 7;
    const int ug  = sub & 3;
    const int kh  = sub >> 2;
    if (row >= B) return;
    const int k0 = kh * 10;

    // Weight slices in VGPRs for all 256 steps (100 floats).
    float whh[5][10], wih[5][10];
#pragma unroll
    for (int u = 0; u < 5; ++u) {
        const int unit = ug * 5 + u;
#pragma unroll
        for (int k2 = 0; k2 < 5; ++k2) {
            float2 a = *(const float2*)(W_hh + unit * 20 + k0 + k2 * 2);
            whh[u][k2 * 2]     = a.x;
            whh[u][k2 * 2 + 1] = a.y;
            float2 b = *(const float2*)(W_ih + unit * 20 + k0 + k2 * 2);
            wih[u][k2 * 2]     = b.x;
            wih[u][k2 * 2 + 1] = b.y;
        }
    }

    float h[10];
#pragma unroll
    for (int i = 0; i < 10; ++i) h[i] = 0.0f;

    const int* xrow = x + (long)row * SEQ;
    int tokA = xrow[0];
    int tokB = xrow[1];
    float eA[10], eB[10];
    float flagA = (tokA != 0) ? 1.0f : 0.0f;
    float flagB;
    {
        const float2* p = (const float2*)(emb + (long)tokA * DIM + k0);
        float2 e0 = p[0], e1 = p[1], e2 = p[2], e3 = p[3], e4 = p[4];
        eA[0] = e0.x; eA[1] = e0.y; eA[2] = e1.x; eA[3] = e1.y;
        eA[4] = e2.x; eA[5] = e2.y; eA[6] = e3.x; eA[7] = e3.y;
        eA[8] = e4.x; eA[9] = e4.y;
    }

    int tokC;
#pragma unroll 1
    for (int s = 0; s < SEQ; s += 2) {
        // step s: consume eA, prefetch eB <- tokB, fetch tokC = x[s+2]
        HALF_STEP(eA, flagA, eB, flagB, tokB, s + 2, tokC)
        // step s+1: consume eB, prefetch eA <- tokC, fetch tokB = x[s+3]
        HALF_STEP(eB, flagB, eA, flagA, tokC, s + 3, tokB)
    }

    // Classifier: lane computes class `ug` partial over its k-half; lane group
    // also computes class 4. Reduce halves, lanes kh==0 write.
    float pc = 0.0f, p4 = 0.0f;
#pragma unroll
    for (int k = 0; k < 10; ++k) {
        pc = fmaf(W_cls[ug * 20 + k0 + k], h[k], pc);
        p4 = fmaf(W_cls[4 * 20 + k0 + k], h[k], p4);
    }
    pc += __shfl_xor(pc, 4, 8);
    p4 += __shfl_xor(p4, 4, 8);
    if (kh == 0) {
        out[(long)row * NCLS + ug] = pc + b_cls[ug];
        if (ug == 0) out[(long)row * NCLS + 4] = p4 + b_cls[4];
    }
}

extern "C" void kernel_launch(void* const* d_in, const int* in_sizes, int n_in,
                              void* d_out, int out_size, void* d_ws, size_t ws_size,
                              hipStream_t stream) {
    const int*   x     = (const int*)d_in[0];
    const float* emb   = (const float*)d_in[1];
    const float* W_ih  = (const float*)d_in[2];
    const float* W_hh  = (const float*)d_in[3];
    const float* W_cls = (const float*)d_in[4];
    const float* b_cls = (const float*)d_in[5];
    float* out = (float*)d_out;

    const int B = in_sizes[0] / SEQ;            // 16384
    const int threads = B * 8;                   // 8 lanes per row
    const int block = 256;
    const int grid = (threads + block - 1) / block;
    rnn_fused<<<grid, block, 0, stream>>>(x, emb, W_ih, W_hh, W_cls, b_cls, out, B);
}

// Round 3
// 148.830 us; speedup vs baseline: 1.3863x; 1.0395x over previous
//
#include <hip/hip_runtime.h>

#define SEQ  256
#define DIM  20
#define NCLS 5

typedef float v2f __attribute__((ext_vector_type(2)));

__device__ __forceinline__ float fast_tanh(float x) {
    // tanh(x) = 1 - 2/(exp(2x)+1); exp(2x) = exp2(x * 2*log2e)
    float e2x = __builtin_amdgcn_exp2f(x * 2.8853900817779268f);
    float r   = __builtin_amdgcn_rcpf(e2x + 1.0f);
    return fmaf(-2.0f, r, 1.0f);
}

__device__ __forceinline__ float bperm(int addr, float v) {
    return __int_as_float(__builtin_amdgcn_ds_bpermute(addr, __float_as_int(v)));
}

// 8 lanes per batch row: sub = lane&7.
//   ug = sub&3  -> owns hidden units [ug*5, ug*5+5)
//   kh = sub>>2 -> owns k-slice pairs [5*kh, 5*kh+5) of every dot product
// All inner math is float2 packed (v_pk_fma_f32): 50 pk_fma per step.
// Embedding prefetched one step ahead (ping-pong), pad flag folded into e.
// h redistribution: 5x shfl_xor (k-half reduce) + 10x ds_bpermute (broadcast).

// STEP: consume ECUR (already flag-scaled), prefetch EPF <- emb[PFTOK],
// fetch NEXTTOK <- xrow[NEXTIDX].
#define STEP(ECUR, EPF, PFTOK, NEXTIDX, NEXTTOK)                               \
    {                                                                          \
        const v2f* _p = (const v2f*)(emb + (long)(PFTOK) * DIM + k0);          \
        v2f _e0 = _p[0], _e1 = _p[1], _e2 = _p[2], _e3 = _p[3], _e4 = _p[4];   \
        const float _fl = ((PFTOK) != 0) ? 1.0f : 0.0f;                        \
        NEXTTOK = xrow[(NEXTIDX) < SEQ ? (NEXTIDX) : (SEQ - 1)];               \
        float _hn[5];                                                          \
        _Pragma("unroll")                                                      \
        for (int u = 0; u < 5; ++u) {                                          \
            v2f _a = ECUR[0] * wih[u][0];                                      \
            _a = __builtin_elementwise_fma(whh[u][0], h2[0], _a);              \
            _Pragma("unroll")                                                  \
            for (int j = 1; j < 5; ++j) {                                      \
                _a = __builtin_elementwise_fma(wih[u][j], ECUR[j], _a);        \
                _a = __builtin_elementwise_fma(whh[u][j], h2[j], _a);          \
            }                                                                  \
            float _s = _a.x + _a.y;                                            \
            _s += __shfl_xor(_s, 4, 8);                                        \
            _hn[u] = _s;                                                       \
        }                                                                      \
        _Pragma("unroll")                                                      \
        for (int u = 0; u < 5; ++u) _hn[u] = fast_tanh(_hn[u]);                \
        h2[0].x = bperm(addrA, _hn[0]); h2[0].y = bperm(addrA, _hn[1]);        \
        h2[1].x = bperm(addrA, _hn[2]); h2[1].y = bperm(addrA, _hn[3]);        \
        h2[2].x = bperm(addrA, _hn[4]); h2[2].y = bperm(addrB, _hn[0]);        \
        h2[3].x = bperm(addrB, _hn[1]); h2[3].y = bperm(addrB, _hn[2]);        \
        h2[4].x = bperm(addrB, _hn[3]); h2[4].y = bperm(addrB, _hn[4]);        \
        EPF[0] = _e0 * _fl; EPF[1] = _e1 * _fl; EPF[2] = _e2 * _fl;            \
        EPF[3] = _e3 * _fl; EPF[4] = _e4 * _fl;                                \
    }

__global__ __launch_bounds__(256, 2)
void rnn_fused(const int* __restrict__ x,
               const float* __restrict__ emb,
               const float* __restrict__ W_ih,
               const float* __restrict__ W_hh,
               const float* __restrict__ W_cls,
               const float* __restrict__ b_cls,
               float* __restrict__ out,
               int B)
{
    const int tid = blockIdx.x * blockDim.x + threadIdx.x;
    const int row = tid >> 3;
    const int sub = tid & 7;
    const int ug  = sub & 3;
    const int kh  = sub >> 2;
    if (row >= B) return;
    const int k0 = kh * 10;

    // ds_bpermute byte addresses: absolute wave lane * 4.
    const int lane  = (int)(threadIdx.x & 63);
    const int addrA = ((lane & ~7) + 2 * kh) << 2;   // source lane for ug'=2kh
    const int addrB = addrA + 4;                     // source lane for ug'=2kh+1

    // Packed weight slices in VGPRs (100 floats = 50 pairs).
    v2f whh[5][5], wih[5][5];
#pragma unroll
    for (int u = 0; u < 5; ++u) {
        const float* ph = W_hh + (ug * 5 + u) * 20 + k0;
        const float* pi = W_ih + (ug * 5 + u) * 20 + k0;
#pragma unroll
        for (int j = 0; j < 5; ++j) {
            whh[u][j] = *(const v2f*)(ph + 2 * j);
            wih[u][j] = *(const v2f*)(pi + 2 * j);
        }
    }

    v2f h2[5];
#pragma unroll
    for (int j = 0; j < 5; ++j) h2[j] = (v2f)(0.0f);

    const int* xrow = x + (long)row * SEQ;
    int tokA = xrow[0];
    int tokB = xrow[1];
    v2f eA[5], eB[5];
    {
        const v2f* p = (const v2f*)(emb + (long)tokA * DIM + k0);
        const float fl = (tokA != 0) ? 1.0f : 0.0f;
        eA[0] = p[0] * fl; eA[1] = p[1] * fl; eA[2] = p[2] * fl;
        eA[3] = p[3] * fl; eA[4] = p[4] * fl;
    }

    int tokC;
#pragma unroll 1
    for (int s = 0; s < SEQ; s += 2) {
        // step s: consume eA, prefetch eB <- tokB, fetch tokC = x[s+2]
        STEP(eA, eB, tokB, s + 2, tokC)
        // step s+1: consume eB, prefetch eA <- tokC, fetch tokB = x[s+3]
        STEP(eB, eA, tokC, s + 3, tokB)
    }

    // Classifier: lane computes class `ug` partial over its k-half; also class 4.
    v2f pc2 = W_cls[ug * 20 + k0] * h2[0].x >= 0.0f ? (v2f)(0.0f) : (v2f)(0.0f); // placeholder avoided below
    {
        const v2f* wc  = (const v2f*)(W_cls + ug * 20 + k0);
        const v2f* wc4 = (const v2f*)(W_cls + 4 * 20 + k0);
        v2f a = wc[0] * h2[0], a4 = wc4[0] * h2[0];
#pragma unroll
        for (int j = 1; j < 5; ++j) {
            a  = __builtin_elementwise_fma(wc[j],  h2[j], a);
            a4 = __builtin_elementwise_fma(wc4[j], h2[j], a4);
        }
        float pc = a.x + a.y;
        float p4 = a4.x + a4.y;
        pc += __shfl_xor(pc, 4, 8);
        p4 += __shfl_xor(p4, 4, 8);
        if (kh == 0) {
            out[(long)row * NCLS + ug] = pc + b_cls[ug];
            if (ug == 0) out[(long)row * NCLS + 4] = p4 + b_cls[4];
        }
    }
}

extern "C" void kernel_launch(void* const* d_in, const int* in_sizes, int n_in,
                              void* d_out, int out_size, void* d_ws, size_t ws_size,
                              hipStream_t stream) {
    const int*   x     = (const int*)d_in[0];
    const float* emb   = (const float*)d_in[1];
    const float* W_ih  = (const float*)d_in[2];
    const float* W_hh  = (const float*)d_in[3];
    const float* W_cls = (const float*)d_in[4];
    const float* b_cls = (const float*)d_in[5];
    float* out = (float*)d_out;

    const int B = in_sizes[0] / SEQ;            // 16384
    const int threads = B * 8;                   // 8 lanes per row
    const int block = 256;
    const int grid = (threads + block - 1) / block;
    rnn_fused<<<grid, block, 0, stream>>>(x, emb, W_ih, W_hh, W_cls, b_cls, out, B);
}

// Round 4
// 148.450 us; speedup vs baseline: 1.3898x; 1.0026x over previous
//
#include <hip/hip_runtime.h>

#define SEQ  256
#define DIM  20
#define NCLS 5

typedef float v2f __attribute__((ext_vector_type(2)));

__device__ __forceinline__ float fast_tanh(float x) {
    // tanh(x) = 1 - 2/(exp(2x)+1); exp(2x) = exp2(x * 2*log2e)
    float e2x = __builtin_amdgcn_exp2f(x * 2.8853900817779268f);
    float r   = __builtin_amdgcn_rcpf(e2x + 1.0f);
    return fmaf(-2.0f, r, 1.0f);
}

__device__ __forceinline__ float bperm(int addr, float v) {
    return __int_as_float(__builtin_amdgcn_ds_bpermute(addr, __float_as_int(v)));
}

// 8 lanes per batch row: sub = lane&7.
//   ug = sub&3  -> owns hidden units [ug*5, ug*5+5)
//   kh = sub>>2 -> owns k-slice pairs [5*kh, 5*kh+5) of every dot product
// All inner math is float2 packed (v_pk_fma_f32): 50 pk_fma per step.
// Weights are PINNED in VGPRs via opaque asm (defeats LLVM remat-reload).
// Embedding prefetched one step ahead (ping-pong), pad flag folded into e.
// h redistribution: 5x shfl_xor (k-half reduce) + 10x ds_bpermute (broadcast).

#define STEP(ECUR, EPF, PFTOK, NEXTIDX, NEXTTOK)                               \
    {                                                                          \
        const v2f* _p = (const v2f*)(emb + (long)(PFTOK) * DIM + k0);          \
        v2f _e0 = _p[0], _e1 = _p[1], _e2 = _p[2], _e3 = _p[3], _e4 = _p[4];   \
        const float _fl = ((PFTOK) != 0) ? 1.0f : 0.0f;                        \
        NEXTTOK = xrow[(NEXTIDX) < SEQ ? (NEXTIDX) : (SEQ - 1)];               \
        float _hn[5];                                                          \
        _Pragma("unroll")                                                      \
        for (int u = 0; u < 5; ++u) {                                          \
            v2f _a = ECUR[0] * wih[u][0];                                      \
            _a = __builtin_elementwise_fma(whh[u][0], h2[0], _a);              \
            _Pragma("unroll")                                                  \
            for (int j = 1; j < 5; ++j) {                                      \
                _a = __builtin_elementwise_fma(wih[u][j], ECUR[j], _a);        \
                _a = __builtin_elementwise_fma(whh[u][j], h2[j], _a);          \
            }                                                                  \
            float _s = _a.x + _a.y;                                            \
            _s += __shfl_xor(_s, 4, 8);                                        \
            _hn[u] = _s;                                                       \
        }                                                                      \
        _Pragma("unroll")                                                      \
        for (int u = 0; u < 5; ++u) _hn[u] = fast_tanh(_hn[u]);                \
        h2[0].x = bperm(addrA, _hn[0]); h2[0].y = bperm(addrA, _hn[1]);        \
        h2[1].x = bperm(addrA, _hn[2]); h2[1].y = bperm(addrA, _hn[3]);        \
        h2[2].x = bperm(addrA, _hn[4]); h2[2].y = bperm(addrB, _hn[0]);        \
        h2[3].x = bperm(addrB, _hn[1]); h2[3].y = bperm(addrB, _hn[2]);        \
        h2[4].x = bperm(addrB, _hn[3]); h2[4].y = bperm(addrB, _hn[4]);        \
        EPF[0] = _e0 * _fl; EPF[1] = _e1 * _fl; EPF[2] = _e2 * _fl;            \
        EPF[3] = _e3 * _fl; EPF[4] = _e4 * _fl;                                \
    }

__global__ __launch_bounds__(256, 2)
void rnn_fused(const int* __restrict__ x,
               const float* __restrict__ emb,
               const float* __restrict__ W_ih,
               const float* __restrict__ W_hh,
               const float* __restrict__ W_cls,
               const float* __restrict__ b_cls,
               float* __restrict__ out,
               int B)
{
    const int tid = blockIdx.x * blockDim.x + threadIdx.x;
    const int row = tid >> 3;
    const int sub = tid & 7;
    const int ug  = sub & 3;
    const int kh  = sub >> 2;
    if (row >= B) return;
    const int k0 = kh * 10;

    // ds_bpermute byte addresses: absolute wave lane * 4.
    const int lane  = (int)(threadIdx.x & 63);
    const int addrA = ((lane & ~7) + 2 * kh) << 2;   // lane holding units [10kh,10kh+5)
    const int addrB = addrA + 4;                     // lane holding units [10kh+5,10kh+10)

    // Packed weight slices in VGPRs (100 floats = 50 pairs), pinned resident.
    v2f whh[5][5], wih[5][5];
#pragma unroll
    for (int u = 0; u < 5; ++u) {
        const float* ph = W_hh + (ug * 5 + u) * 20 + k0;
        const float* pi = W_ih + (ug * 5 + u) * 20 + k0;
#pragma unroll
        for (int j = 0; j < 5; ++j) {
            whh[u][j] = *(const v2f*)(ph + 2 * j);
            wih[u][j] = *(const v2f*)(pi + 2 * j);
        }
    }
    // Opaque pin: values become asm outputs -> not rematerializable, must
    // stay in VGPRs across all 256 steps instead of being reloaded from L1.
#pragma unroll
    for (int u = 0; u < 5; ++u) {
#pragma unroll
        for (int j = 0; j < 5; ++j) {
            asm volatile("" : "+v"(whh[u][j]));
            asm volatile("" : "+v"(wih[u][j]));
        }
    }

    v2f h2[5];
#pragma unroll
    for (int j = 0; j < 5; ++j) h2[j] = (v2f)(0.0f);

    const int* xrow = x + (long)row * SEQ;
    int tokA = xrow[0];
    int tokB = xrow[1];
    v2f eA[5], eB[5];
    {
        const v2f* p = (const v2f*)(emb + (long)tokA * DIM + k0);
        const float fl = (tokA != 0) ? 1.0f : 0.0f;
        eA[0] = p[0] * fl; eA[1] = p[1] * fl; eA[2] = p[2] * fl;
        eA[3] = p[3] * fl; eA[4] = p[4] * fl;
    }

    int tokC;
#pragma unroll 1
    for (int s = 0; s < SEQ; s += 2) {
        // step s: consume eA, prefetch eB <- tokB, fetch tokC = x[s+2]
        STEP(eA, eB, tokB, s + 2, tokC)
        // step s+1: consume eB, prefetch eA <- tokC, fetch tokB = x[s+3]
        STEP(eB, eA, tokC, s + 3, tokB)
    }

    // Classifier: lane computes class `ug` partial over its k-half; also class 4.
    {
        const v2f* wc  = (const v2f*)(W_cls + ug * 20 + k0);
        const v2f* wc4 = (const v2f*)(W_cls + 4 * 20 + k0);
        v2f a = wc[0] * h2[0], a4 = wc4[0] * h2[0];
#pragma unroll
        for (int j = 1; j < 5; ++j) {
            a  = __builtin_elementwise_fma(wc[j],  h2[j], a);
            a4 = __builtin_elementwise_fma(wc4[j], h2[j], a4);
        }
        float pc = a.x + a.y;
        float p4 = a4.x + a4.y;
        pc += __shfl_xor(pc, 4, 8);
        p4 += __shfl_xor(p4, 4, 8);
        if (kh == 0) {
            out[(long)row * NCLS + ug] = pc + b_cls[ug];
            if (ug == 0) out[(long)row * NCLS + 4] = p4 + b_cls[4];
        }
    }
}

extern "C" void kernel_launch(void* const* d_in, const int* in_sizes, int n_in,
                              void* d_out, int out_size, void* d_ws, size_t ws_size,
                              hipStream_t stream) {
    const int*   x     = (const int*)d_in[0];
    const float* emb   = (const float*)d_in[1];
    const float* W_ih  = (const float*)d_in[2];
    const float* W_hh  = (const float*)d_in[3];
    const float* W_cls = (const float*)d_in[4];
    const float* b_cls = (const float*)d_in[5];
    float* out = (float*)d_out;

    const int B = in_sizes[0] / SEQ;            // 16384
    const int threads = B * 8;                   // 8 lanes per row
    const int block = 256;
    const int grid = (threads + block - 1) / block;
    rnn_fused<<<grid, block, 0, stream>>>(x, emb, W_ih, W_hh, W_cls, b_cls, out, B);
}